// Round 1
// baseline (565.160 us; speedup 1.0000x reference)
//
#include <hip/hip_runtime.h>
#include <cstdint>

static __device__ __forceinline__ float sigmoidf_(float x) { return 1.f / (1.f + __expf(-x)); }

// ---------------- K1: 1x1 conv (proj) + BN0 + ReLU -> p_tok (b,l,32), p_nchw (b,32,l) ----
__global__ __launch_bounds__(256) void k_proj_bn(
    const float* __restrict__ x, const float* __restrict__ w,
    const float* __restrict__ pb,
    const float* __restrict__ g, const float* __restrict__ be,
    const float* __restrict__ mm, const float* __restrict__ vv,
    float* __restrict__ p_tok, float* __restrict__ p_nchw)
{
  __shared__ float wl[6400];        // [c][d] transposed proj_w
  __shared__ float sc[32], sb[32];
  int b = blockIdx.x >> 2, ch = blockIdx.x & 3;
  for (int i = threadIdx.x; i < 6400; i += 256) {
    int c = i >> 5, d = i & 31;
    wl[i] = w[d * 200 + c];
  }
  if (threadIdx.x < 32) {
    int d = threadIdx.x;
    float s = g[d] * rsqrtf(vv[d] + 1e-5f);
    sc[d] = s;
    sb[d] = fmaf(pb[d] - mm[d], s, be[d]);   // fold proj_b into BN shift
  }
  __syncthreads();
  int l = (ch << 8) + threadIdx.x;
  const float* xp = x + (size_t)b * 200 * 1024 + l;
  float acc[32];
  #pragma unroll
  for (int d = 0; d < 32; d++) acc[d] = 0.f;
  for (int c = 0; c < 200; c++) {
    float xv = xp[(size_t)c << 10];
    const float* wr = &wl[c << 5];
    #pragma unroll
    for (int d = 0; d < 32; d++) acc[d] = fmaf(xv, wr[d], acc[d]);
  }
  float* pn = p_nchw + ((size_t)b << 15) + l;
  #pragma unroll
  for (int d = 0; d < 32; d++) {
    float val = fmaf(acc[d], sc[d], sb[d]);
    val = fmaxf(val, 0.f);
    acc[d] = val;
    pn[(size_t)d << 10] = val;
  }
  float* pt = p_tok + (((size_t)b << 10) + l) * 32;
  #pragma unroll
  for (int d = 0; d < 32; d += 4)
    *reinterpret_cast<float4*>(pt + d) = make_float4(acc[d], acc[d+1], acc[d+2], acc[d+3]);
}

// ------------- K2a: in_proj -> causal dwconv4 -> silu -> x_proj -> delta/B/C, silu(z) ----
// one block = (b, 64-token chunk); phase-union'd LDS (<= 53 KB)
__global__ __launch_bounds__(256) void k_mamba_pre(
    const float* __restrict__ p_tok,
    const float* __restrict__ in_w,     // (128,32)
    const float* __restrict__ conv_w,   // (64,4)
    const float* __restrict__ conv_b,   // (64)
    const float* __restrict__ xp_w,     // (34,64)
    const float* __restrict__ dt_w,     // (64,2)
    const float* __restrict__ dt_b,     // (64)
    float* __restrict__ u_out, float* __restrict__ zs_out,
    float* __restrict__ delta_out, float* __restrict__ B_out, float* __restrict__ C_out)
{
  __shared__ __align__(16) char smem[52992];
  float* tok  = (float*)smem;              // [67][32]  phase1 (8576 B)
  float* winT = (float*)(smem + 8576);     // [32][128] phase1 (16384 B)
  float* uL   = (float*)smem;              // [64][64]  phase2+ (aliases tok/winT)
  float* xdbl = (float*)(smem + 16384);    // [64][34]  phase3+ (aliases winT tail)
  float* xm   = (float*)(smem + 25088);    // [67][64]
  float* xpwT = (float*)(smem + 42240);    // [64][34]
  float* cw   = (float*)(smem + 50944);    // [64][4]
  float* cb   = (float*)(smem + 51968);    // [64]
  float* dtw  = (float*)(smem + 52224);    // [64][2]
  float* dtb  = (float*)(smem + 52736);    // [64]

  int b = blockIdx.x >> 4, chk = blockIdx.x & 15;
  int t0 = chk << 6;
  int tid = threadIdx.x;

  for (int i = tid; i < 4096; i += 256) {        // winT[c][o] = in_w[o][c]
    int o = i & 127, c = i >> 7;
    winT[(c << 7) + o] = in_w[(o << 5) + c];
  }
  for (int i = tid; i < 2176; i += 256) {        // xpwT[o][j] = xp_w[j][o]
    int o = i & 63, j = i >> 6;
    xpwT[o * 34 + j] = xp_w[(j << 6) + o];
  }
  if (tid < 64) {
    cb[tid] = conv_b[tid]; dtb[tid] = dt_b[tid];
    dtw[2*tid] = dt_w[2*tid]; dtw[2*tid+1] = dt_w[2*tid+1];
    #pragma unroll
    for (int q = 0; q < 4; q++) cw[4*tid+q] = conv_w[4*tid+q];
  }
  for (int i = tid; i < 2144; i += 256) {        // tokens t0-3 .. t0+63
    int r = i >> 5, c = i & 31;
    int tg = t0 + r - 3;
    tok[i] = (tg >= 0) ? p_tok[((((size_t)b << 10) + tg) << 5) + c] : 0.f;
  }
  __syncthreads();
  // phase1: xz = tok @ in_w^T ; xm -> LDS, silu(z) -> global
  {
    int o = tid & 127, half = tid >> 7;
    for (int r = half; r < 67; r += 2) {
      float a = 0.f;
      const float* tr = &tok[r << 5];
      #pragma unroll
      for (int c = 0; c < 32; c++) a = fmaf(tr[c], winT[(c << 7) + o], a);
      if (o < 64) xm[(r << 6) + o] = a;
      else if (r >= 3) {
        float s = a * sigmoidf_(a);
        zs_out[((((size_t)b << 10) + (t0 + r - 3)) << 6) + (o - 64)] = s;
      }
    }
  }
  __syncthreads();
  // phase2: depthwise causal conv(4) + silu -> u
  {
    int o = tid & 63, tq = tid >> 6;
    float w0 = cw[4*o], w1 = cw[4*o+1], w2 = cw[4*o+2], w3 = cw[4*o+3], bb = cb[o];
    for (int t = tq; t < 64; t += 4) {
      float a = bb;
      a = fmaf(w0, xm[( t      << 6) + o], a);
      a = fmaf(w1, xm[((t + 1) << 6) + o], a);
      a = fmaf(w2, xm[((t + 2) << 6) + o], a);
      a = fmaf(w3, xm[((t + 3) << 6) + o], a);
      float uu = a * sigmoidf_(a);
      uL[(t << 6) + o] = uu;
      u_out[((((size_t)b << 10) + (t0 + t)) << 6) + o] = uu;
    }
  }
  __syncthreads();
  // phase3: xdbl = u @ xp_w^T  (34 outputs)
  for (int idx = tid; idx < 2176; idx += 256) {
    int t = idx / 34, j = idx - t * 34;
    float a = 0.f;
    const float* ur = &uL[t << 6];
    #pragma unroll
    for (int o = 0; o < 64; o++) a = fmaf(ur[o], xpwT[o * 34 + j], a);
    xdbl[t * 34 + j] = a;
  }
  __syncthreads();
  // phase4: delta = softplus(dt @ dt_w^T + dt_b); write B, C
  {
    int d = tid & 63, tq = tid >> 6;
    float wd0 = dtw[2*d], wd1 = dtw[2*d+1], bbd = dtb[d];
    for (int t = tq; t < 64; t += 4) {
      float pre = fmaf(xdbl[t*34], wd0, fmaf(xdbl[t*34+1], wd1, bbd));
      float dl = (pre > 20.f) ? pre : log1pf(__expf(pre));
      delta_out[((((size_t)b << 10) + (t0 + t)) << 6) + d] = dl;
    }
  }
  for (int idx = tid; idx < 2048; idx += 256) {
    int t = idx >> 5, j = idx & 31;
    float val = xdbl[t*34 + 2 + j];
    size_t base = (((size_t)b << 10) + (t0 + t)) << 4;
    if (j < 16) B_out[base + j] = val;
    else        C_out[base + j - 16] = val;
  }
}

// ---------------- K2b: selective scan; thread=(d,n); accumulate ybar directly ------------
__global__ __launch_bounds__(1024) void k_scan(
    const float* __restrict__ u, const float* __restrict__ zs,
    const float* __restrict__ delta, const float* __restrict__ Bm,
    const float* __restrict__ Cm, const float* __restrict__ A_log,
    const float* __restrict__ Dp, float* __restrict__ ybar)
{
  __shared__ float dlT[64][68], uT[64][68], zT[64][68], BT[16][68], CT[16][68];
  int b = blockIdx.x;
  int tid = threadIdx.x;
  int d = tid >> 4, n = tid & 15;
  float A = -__expf(A_log[(d << 4) + n]);
  float h = 0.f, acc_n = 0.f, acc_u = 0.f;
  const float* ub = u     + ((size_t)b << 16);
  const float* zb = zs    + ((size_t)b << 16);
  const float* db = delta + ((size_t)b << 16);
  const float* Bb = Bm    + ((size_t)b << 14);
  const float* Cb = Cm    + ((size_t)b << 14);
  for (int c = 0; c < 16; c++) {
    __syncthreads();
    for (int i = tid; i < 4096; i += 1024) {   // transpose chunk to [d][t]
      int t = i >> 6, dd = i & 63;
      dlT[dd][t] = db[(c << 12) + i];
      uT [dd][t] = ub[(c << 12) + i];
      zT [dd][t] = zb[(c << 12) + i];
    }
    {
      int t = tid >> 4, nn = tid & 15;
      BT[nn][t] = Bb[(c << 10) + tid];
      CT[nn][t] = Cb[(c << 10) + tid];
    }
    __syncthreads();
    for (int tq = 0; tq < 64; tq += 4) {
      float4 dv = *reinterpret_cast<const float4*>(&dlT[d][tq]);
      float4 uv = *reinterpret_cast<const float4*>(&uT[d][tq]);
      float4 zv = *reinterpret_cast<const float4*>(&zT[d][tq]);
      float4 Bv = *reinterpret_cast<const float4*>(&BT[n][tq]);
      float4 Cv = *reinterpret_cast<const float4*>(&CT[n][tq]);
      h = fmaf(__expf(dv.x * A), h, dv.x * uv.x * Bv.x);
      acc_n = fmaf(h * Cv.x, zv.x, acc_n);  acc_u = fmaf(uv.x, zv.x, acc_u);
      h = fmaf(__expf(dv.y * A), h, dv.y * uv.y * Bv.y);
      acc_n = fmaf(h * Cv.y, zv.y, acc_n);  acc_u = fmaf(uv.y, zv.y, acc_u);
      h = fmaf(__expf(dv.z * A), h, dv.z * uv.z * Bv.z);
      acc_n = fmaf(h * Cv.z, zv.z, acc_n);  acc_u = fmaf(uv.z, zv.z, acc_u);
      h = fmaf(__expf(dv.w * A), h, dv.w * uv.w * Bv.w);
      acc_n = fmaf(h * Cv.w, zv.w, acc_n);  acc_u = fmaf(uv.w, zv.w, acc_u);
    }
  }
  float y_n = acc_n;
  #pragma unroll
  for (int o = 8; o >= 1; o >>= 1) y_n += __shfl_xor(y_n, o, 16);
  if (n == 0) ybar[(b << 6) + d] = (y_n + Dp[d] * acc_u) * (1.f / 1024.f);
}

// ---------------- K3a: conv1 3x3 VALID (32->32) + BN1 + ReLU ----------------
__global__ __launch_bounds__(320) void k_conv1(
    const float* __restrict__ p_nchw, const float* __restrict__ w,
    const float* __restrict__ cbias,
    const float* __restrict__ g, const float* __restrict__ be,
    const float* __restrict__ mm, const float* __restrict__ vv,
    float* __restrict__ c1out)
{
  __shared__ float wlT[288][32];     // [k][co]
  __shared__ float inl[32][4][32];   // [ci][row][x]
  __shared__ float sc[32], sb[32];
  int b = blockIdx.x / 15, yp = blockIdx.x % 15;
  int tid = threadIdx.x;
  for (int i = tid; i < 9216; i += 320) {
    int co = i & 31, k = i >> 5;
    wlT[k][co] = w[co * 288 + k];
  }
  if (tid < 32) {
    float s = g[tid] * rsqrtf(vv[tid] + 1e-5f);
    sc[tid] = s;
    sb[tid] = fmaf(cbias[tid] - mm[tid], s, be[tid]);
  }
  int y0 = yp * 2;
  for (int i = tid; i < 4096; i += 320) {
    int ci = i >> 7, r = (i >> 5) & 3, xc = i & 31;
    inl[ci][r][xc] = p_nchw[((size_t)b << 15) + ((size_t)ci << 10) + ((size_t)(y0 + r) << 5) + xc];
  }
  __syncthreads();
  int xs = tid % 5, y = (tid / 5) & 1, co = tid / 10;   // 320 tasks exactly
  int x0 = xs * 6;
  float acc[6] = {0,0,0,0,0,0};
  for (int ci = 0; ci < 32; ci++) {
    #pragma unroll
    for (int dy = 0; dy < 3; dy++) {
      const float* base = &inl[ci][y + dy][x0];
      float rr[8];
      #pragma unroll
      for (int q = 0; q < 8; q++) rr[q] = base[q];
      const int kb = ci * 9 + dy * 3;
      #pragma unroll
      for (int dx = 0; dx < 3; dx++) {
        float wv = wlT[kb + dx][co];
        #pragma unroll
        for (int k = 0; k < 6; k++) acc[k] = fmaf(wv, rr[dx + k], acc[k]);
      }
    }
  }
  float s = sc[co], bb = sb[co];
  size_t ob = ((size_t)b * 32 + co) * 900 + (size_t)(y0 + y) * 30 + x0;
  #pragma unroll
  for (int k = 0; k < 6; k++) {
    float val = fmaf(acc[k], s, bb);
    c1out[ob + k] = fmaxf(val, 0.f);
  }
}

// ---------------- K3b: conv2 3x3 VALID (32->128) + BN2 + ReLU + spatial-sum ----------------
__global__ __launch_bounds__(128) void k_conv2(
    const float* __restrict__ c1out, const float* __restrict__ w2,
    const float* __restrict__ cb2,
    const float* __restrict__ g, const float* __restrict__ be,
    const float* __restrict__ mm, const float* __restrict__ vv,
    float* __restrict__ cnn_sum)
{
  __shared__ float wT[288][32];      // [k][co_local]
  __shared__ float in2[32][6][30];   // strip of 6 input rows
  __shared__ float sc[32], sb[32];
  __shared__ float red[8][4][16];
  int b = blockIdx.x >> 2, cog = blockIdx.x & 3;
  int tid = threadIdx.x;
  for (int i = tid; i < 9216; i += 128) {
    int col = i & 31, k = i >> 5;
    wT[k][col] = w2[((size_t)(cog * 32 + col)) * 288 + k];
  }
  if (tid < 32) {
    int co = cog * 32 + tid;
    float s = g[co] * rsqrtf(vv[co] + 1e-5f);
    sc[tid] = s;
    sb[tid] = fmaf(cb2[co] - mm[co], s, be[co]);
  }
  int xs = tid & 3, y = (tid >> 2) & 3, coq = tid >> 4;  // 128 tasks exactly
  int x0 = xs * 7;
  float psum[4] = {0,0,0,0};
  for (int st = 0; st < 7; st++) {
    __syncthreads();
    for (int i = tid; i < 5760; i += 128) {
      int ci = i / 180, rr_ = i % 180; int r = rr_ / 30, xc = rr_ % 30;
      in2[ci][r][xc] = c1out[((size_t)b * 32 + ci) * 900 + (size_t)(st * 4 + r) * 30 + xc];
    }
    __syncthreads();
    float acc[4][7];
    #pragma unroll
    for (int j = 0; j < 4; j++)
      #pragma unroll
      for (int k = 0; k < 7; k++) acc[j][k] = 0.f;
    for (int ci = 0; ci < 32; ci++) {
      #pragma unroll
      for (int dy = 0; dy < 3; dy++) {
        const float* base = &in2[ci][y + dy][x0];
        float rr[9];
        #pragma unroll
        for (int q = 0; q < 9; q++) rr[q] = base[q];
        const int kb = ci * 9 + dy * 3;
        #pragma unroll
        for (int dx = 0; dx < 3; dx++) {
          float4 wv = *reinterpret_cast<const float4*>(&wT[kb + dx][coq * 4]);
          #pragma unroll
          for (int k = 0; k < 7; k++) {
            float iv = rr[dx + k];
            acc[0][k] = fmaf(wv.x, iv, acc[0][k]);
            acc[1][k] = fmaf(wv.y, iv, acc[1][k]);
            acc[2][k] = fmaf(wv.z, iv, acc[2][k]);
            acc[3][k] = fmaf(wv.w, iv, acc[3][k]);
          }
        }
      }
    }
    #pragma unroll
    for (int j = 0; j < 4; j++) {
      int col = coq * 4 + j;
      float s = sc[col], bb = sb[col];
      #pragma unroll
      for (int k = 0; k < 7; k++) {
        float val = fmaf(acc[j][k], s, bb);
        psum[j] += fmaxf(val, 0.f);
      }
    }
  }
  __syncthreads();
  #pragma unroll
  for (int j = 0; j < 4; j++) red[coq][j][y * 4 + xs] = psum[j];
  __syncthreads();
  if (tid < 32) {
    int cq = tid >> 2, j = tid & 3;
    float s = 0.f;
    #pragma unroll
    for (int q = 0; q < 16; q++) s += red[cq][j][q];
    cnn_sum[((size_t)b << 7) + cog * 32 + cq * 4 + j] = s;
  }
}

// ---------------- K4a: W2 = fc_w @ out_proj_w  (128 x 64) ----------------
__global__ __launch_bounds__(256) void k_w2(
    const float* __restrict__ fc_w, const float* __restrict__ opw, float* __restrict__ W2)
{
  int i = blockIdx.x * 256 + threadIdx.x;
  if (i < 8192) {
    int f = i >> 6, d2 = i & 63;
    float a = 0.f;
    #pragma unroll
    for (int dm = 0; dm < 32; dm++) a = fmaf(fc_w[(f << 5) + dm], opw[(dm << 6) + d2], a);
    W2[i] = a;
  }
}

// ---------------- K4b: out = ybar @ W2^T + fc_b + cnn_sum/784 ----------------
__global__ __launch_bounds__(256) void k_final(
    const float* __restrict__ ybar, const float* __restrict__ W2,
    const float* __restrict__ fc_b, const float* __restrict__ cnn_sum,
    float* __restrict__ out)
{
  int i = blockIdx.x * 256 + threadIdx.x;   // 16384
  int b = i >> 7, f = i & 127;
  float a = 0.f;
  #pragma unroll
  for (int d2 = 0; d2 < 64; d2++) a = fmaf(ybar[(b << 6) + d2], W2[(f << 6) + d2], a);
  out[i] = a + fc_b[f] + cnn_sum[i] * (1.f / 784.f);
}

extern "C" void kernel_launch(void* const* d_in, const int* in_sizes, int n_in,
                              void* d_out, int out_size, void* d_ws, size_t ws_size,
                              hipStream_t stream) {
  (void)in_sizes; (void)n_in; (void)out_size; (void)ws_size;
  const float* x         = (const float*)d_in[0];
  const float* proj_w    = (const float*)d_in[1];
  const float* proj_b    = (const float*)d_in[2];
  const float* bn0_g     = (const float*)d_in[3];
  const float* bn0_b     = (const float*)d_in[4];
  const float* bn0_m     = (const float*)d_in[5];
  const float* bn0_v     = (const float*)d_in[6];
  const float* in_proj_w = (const float*)d_in[7];
  const float* conv_w    = (const float*)d_in[8];
  const float* conv_b    = (const float*)d_in[9];
  const float* x_proj_w  = (const float*)d_in[10];
  const float* dt_w      = (const float*)d_in[11];
  const float* dt_b      = (const float*)d_in[12];
  const float* A_log     = (const float*)d_in[13];
  const float* Dp        = (const float*)d_in[14];
  const float* out_proj_w= (const float*)d_in[15];
  const float* fc_w      = (const float*)d_in[16];
  const float* fc_b      = (const float*)d_in[17];
  const float* c1_w      = (const float*)d_in[18];
  const float* c1_b      = (const float*)d_in[19];
  const float* bn1_g     = (const float*)d_in[20];
  const float* bn1_b     = (const float*)d_in[21];
  const float* bn1_m     = (const float*)d_in[22];
  const float* bn1_v     = (const float*)d_in[23];
  const float* c2_w      = (const float*)d_in[24];
  const float* c2_b      = (const float*)d_in[25];
  const float* bn2_g     = (const float*)d_in[26];
  const float* bn2_b     = (const float*)d_in[27];
  const float* bn2_m     = (const float*)d_in[28];
  const float* bn2_v     = (const float*)d_in[29];
  float* out = (float*)d_out;
  float* ws  = (float*)d_ws;
  // workspace layout (floats); total ~41.47M floats = 166 MB
  float* p_tok   = ws;               // 4194304
  float* p_nchw  = ws + 4194304;     // 4194304
  float* u_b     = ws + 8388608;     // 8388608
  float* delta_b = ws + 16777216;    // 8388608
  float* zs_b    = ws + 25165824;    // 8388608
  float* Bm      = ws + 33554432;    // 2097152
  float* Cm      = ws + 35651584;    // 2097152
  float* c1o     = ws + 37748736;    // 3686400
  float* ybar    = ws + 41435136;    // 8192
  float* cnn_sum = ws + 41443328;    // 16384
  float* W2      = ws + 41459712;    // 8192

  k_proj_bn<<<dim3(512), dim3(256), 0, stream>>>(x, proj_w, proj_b, bn0_g, bn0_b, bn0_m, bn0_v, p_tok, p_nchw);
  k_mamba_pre<<<dim3(2048), dim3(256), 0, stream>>>(p_tok, in_proj_w, conv_w, conv_b, x_proj_w, dt_w, dt_b,
                                                    u_b, zs_b, delta_b, Bm, Cm);
  k_scan<<<dim3(128), dim3(1024), 0, stream>>>(u_b, zs_b, delta_b, Bm, Cm, A_log, Dp, ybar);
  k_conv1<<<dim3(1920), dim3(320), 0, stream>>>(p_nchw, c1_w, c1_b, bn1_g, bn1_b, bn1_m, bn1_v, c1o);
  k_conv2<<<dim3(512), dim3(128), 0, stream>>>(c1o, c2_w, c2_b, bn2_g, bn2_b, bn2_m, bn2_v, cnn_sum);
  k_w2<<<dim3(32), dim3(256), 0, stream>>>(fc_w, out_proj_w, W2);
  k_final<<<dim3(64), dim3(256), 0, stream>>>(ybar, W2, fc_b, cnn_sum, out);
}

// Round 2
// 269.133 us; speedup vs baseline: 2.0999x; 2.0999x over previous
//
#include <hip/hip_runtime.h>
#include <cstdint>

typedef short bf16x8 __attribute__((ext_vector_type(8)));
typedef float f32x4 __attribute__((ext_vector_type(4)));
#define MFMA16(a, b, c) __builtin_amdgcn_mfma_f32_16x16x32_bf16((a), (b), (c), 0, 0, 0)

static __device__ __forceinline__ float sigmoidf_(float x) { return 1.f / (1.f + __expf(-x)); }
static __device__ __forceinline__ unsigned short f2bf(float f) {
  union { float f; unsigned u; } v; v.f = f;
  unsigned r = v.u + 0x7FFF + ((v.u >> 16) & 1);
  return (unsigned short)(r >> 16);
}

// ---------------- K0: weight prep (frag layouts for MFMA convs), W2, zero cnn_sum -------
__global__ __launch_bounds__(256) void k_prep(
    const float* __restrict__ c1_w, const float* __restrict__ c2_w,
    const float* __restrict__ fc_w, const float* __restrict__ opw,
    unsigned short* __restrict__ Wf1, unsigned short* __restrict__ Wf2,
    float* __restrict__ W2, float* __restrict__ cnn_sum)
{
  int i = blockIdx.x * 256 + threadIdx.x;
  if (i < 36864) {           // Wf2[t][cf 0..7][lane][j] = c2_w[co][ci][dy][dx]
    int j = i & 7, l = (i >> 3) & 63, m = (i >> 9) & 7, t = i >> 12;
    int co = m * 16 + (l & 15), ci = ((l >> 4) << 3) + j;
    Wf2[i] = f2bf(c2_w[(size_t)(co * 32 + ci) * 9 + t]);
  } else if (i < 46080) {    // Wf1[t][cf 0..1][lane][j]
    int ii = i - 36864;
    int j = ii & 7, l = (ii >> 3) & 63, m = (ii >> 9) & 1, t = ii >> 10;
    int co = m * 16 + (l & 15), ci = ((l >> 4) << 3) + j;
    Wf1[ii] = f2bf(c1_w[(size_t)(co * 32 + ci) * 9 + t]);
  } else if (i < 54272) {    // W2 = fc_w @ out_proj_w (128x64)
    int ii = i - 46080;
    int f = ii >> 6, d2 = ii & 63;
    float a = 0.f;
    #pragma unroll
    for (int dm = 0; dm < 32; dm++) a = fmaf(fc_w[(f << 5) + dm], opw[(dm << 6) + d2], a);
    W2[ii] = a;
  } else if (i < 70656) {
    cnn_sum[i - 54272] = 0.f;
  }
}

// ---------------- K1: 1x1 conv (proj) + BN0 + ReLU -> p_tok (f32), p_bf (bf16) ----------
__global__ __launch_bounds__(256) void k_proj_bn(
    const float* __restrict__ x, const float* __restrict__ w,
    const float* __restrict__ pb,
    const float* __restrict__ g, const float* __restrict__ be,
    const float* __restrict__ mm, const float* __restrict__ vv,
    float* __restrict__ p_tok, unsigned short* __restrict__ p_bf)
{
  __shared__ float wl[6400];        // [c][d] transposed proj_w
  __shared__ float sc[32], sb[32];
  int b = blockIdx.x >> 2, ch = blockIdx.x & 3;
  for (int i = threadIdx.x; i < 6400; i += 256) {
    int c = i >> 5, d = i & 31;
    wl[i] = w[d * 200 + c];
  }
  if (threadIdx.x < 32) {
    int d = threadIdx.x;
    float s = g[d] * rsqrtf(vv[d] + 1e-5f);
    sc[d] = s;
    sb[d] = fmaf(pb[d] - mm[d], s, be[d]);
  }
  __syncthreads();
  int l = (ch << 8) + threadIdx.x;
  const float* xp = x + (size_t)b * 200 * 1024 + l;
  float acc[32];
  #pragma unroll
  for (int d = 0; d < 32; d++) acc[d] = 0.f;
  for (int c = 0; c < 200; c++) {
    float xv = xp[(size_t)c << 10];
    const float* wr = &wl[c << 5];
    #pragma unroll
    for (int d = 0; d < 32; d++) acc[d] = fmaf(xv, wr[d], acc[d]);
  }
  #pragma unroll
  for (int d = 0; d < 32; d++) {
    float val = fmaf(acc[d], sc[d], sb[d]);
    acc[d] = fmaxf(val, 0.f);
  }
  float* pt = p_tok + (((size_t)b << 10) + l) * 32;
  #pragma unroll
  for (int d = 0; d < 32; d += 4)
    *reinterpret_cast<float4*>(pt + d) = make_float4(acc[d], acc[d+1], acc[d+2], acc[d+3]);
  unsigned short* pbf = p_bf + (((size_t)b << 10) + l) * 32;
  #pragma unroll
  for (int k = 0; k < 4; k++) {
    uint4 q;
    q.x = (unsigned)f2bf(acc[8*k+0]) | ((unsigned)f2bf(acc[8*k+1]) << 16);
    q.y = (unsigned)f2bf(acc[8*k+2]) | ((unsigned)f2bf(acc[8*k+3]) << 16);
    q.z = (unsigned)f2bf(acc[8*k+4]) | ((unsigned)f2bf(acc[8*k+5]) << 16);
    q.w = (unsigned)f2bf(acc[8*k+6]) | ((unsigned)f2bf(acc[8*k+7]) << 16);
    *reinterpret_cast<uint4*>(pbf + k * 8) = q;
  }
}

// ------------- K2a: in_proj -> causal dwconv4 -> silu -> x_proj -> delta/B/C, silu(z) ----
__global__ __launch_bounds__(256) void k_mamba_pre(
    const float* __restrict__ p_tok,
    const float* __restrict__ in_w,
    const float* __restrict__ conv_w,
    const float* __restrict__ conv_b,
    const float* __restrict__ xp_w,
    const float* __restrict__ dt_w,
    const float* __restrict__ dt_b,
    float* __restrict__ u_out, float* __restrict__ zs_out,
    float* __restrict__ delta_out, float* __restrict__ B_out, float* __restrict__ C_out)
{
  __shared__ __align__(16) char smem[52992];
  float* tok  = (float*)smem;              // [67][32]
  float* winT = (float*)(smem + 8576);     // [32][128]
  float* uL   = (float*)smem;              // [64][64]  (aliases)
  float* xdbl = (float*)(smem + 16384);    // [64][34]
  float* xm   = (float*)(smem + 25088);    // [67][64]
  float* xpwT = (float*)(smem + 42240);    // [64][34]
  float* cw   = (float*)(smem + 50944);
  float* cb   = (float*)(smem + 51968);
  float* dtw  = (float*)(smem + 52224);
  float* dtb  = (float*)(smem + 52736);

  int b = blockIdx.x >> 4, chk = blockIdx.x & 15;
  int t0 = chk << 6;
  int tid = threadIdx.x;

  for (int i = tid; i < 4096; i += 256) {
    int o = i & 127, c = i >> 7;
    winT[(c << 7) + o] = in_w[(o << 5) + c];
  }
  for (int i = tid; i < 2176; i += 256) {
    int o = i & 63, j = i >> 6;
    xpwT[o * 34 + j] = xp_w[(j << 6) + o];
  }
  if (tid < 64) {
    cb[tid] = conv_b[tid]; dtb[tid] = dt_b[tid];
    dtw[2*tid] = dt_w[2*tid]; dtw[2*tid+1] = dt_w[2*tid+1];
    #pragma unroll
    for (int q = 0; q < 4; q++) cw[4*tid+q] = conv_w[4*tid+q];
  }
  for (int i = tid; i < 2144; i += 256) {
    int r = i >> 5, c = i & 31;
    int tg = t0 + r - 3;
    tok[i] = (tg >= 0) ? p_tok[((((size_t)b << 10) + tg) << 5) + c] : 0.f;
  }
  __syncthreads();
  {
    int o = tid & 127, half = tid >> 7;
    for (int r = half; r < 67; r += 2) {
      float a = 0.f;
      const float* tr = &tok[r << 5];
      #pragma unroll
      for (int c = 0; c < 32; c++) a = fmaf(tr[c], winT[(c << 7) + o], a);
      if (o < 64) xm[(r << 6) + o] = a;
      else if (r >= 3) {
        float s = a * sigmoidf_(a);
        zs_out[((((size_t)b << 10) + (t0 + r - 3)) << 6) + (o - 64)] = s;
      }
    }
  }
  __syncthreads();
  {
    int o = tid & 63, tq = tid >> 6;
    float w0 = cw[4*o], w1 = cw[4*o+1], w2 = cw[4*o+2], w3 = cw[4*o+3], bb = cb[o];
    for (int t = tq; t < 64; t += 4) {
      float a = bb;
      a = fmaf(w0, xm[( t      << 6) + o], a);
      a = fmaf(w1, xm[((t + 1) << 6) + o], a);
      a = fmaf(w2, xm[((t + 2) << 6) + o], a);
      a = fmaf(w3, xm[((t + 3) << 6) + o], a);
      float uu = a * sigmoidf_(a);
      uL[(t << 6) + o] = uu;
      u_out[((((size_t)b << 10) + (t0 + t)) << 6) + o] = uu;
    }
  }
  __syncthreads();
  for (int idx = tid; idx < 2176; idx += 256) {
    int t = idx / 34, j = idx - t * 34;
    float a = 0.f;
    const float* ur = &uL[t << 6];
    #pragma unroll
    for (int o = 0; o < 64; o++) a = fmaf(ur[o], xpwT[o * 34 + j], a);
    xdbl[t * 34 + j] = a;
  }
  __syncthreads();
  {
    int d = tid & 63, tq = tid >> 6;
    float wd0 = dtw[2*d], wd1 = dtw[2*d+1], bbd = dtb[d];
    for (int t = tq; t < 64; t += 4) {
      float pre = fmaf(xdbl[t*34], wd0, fmaf(xdbl[t*34+1], wd1, bbd));
      float dl = (pre > 20.f) ? pre : log1pf(__expf(pre));
      delta_out[((((size_t)b << 10) + (t0 + t)) << 6) + d] = dl;
    }
  }
  for (int idx = tid; idx < 2048; idx += 256) {
    int t = idx >> 5, j = idx & 31;
    float val = xdbl[t*34 + 2 + j];
    size_t base = (((size_t)b << 10) + (t0 + t)) << 4;
    if (j < 16) B_out[base + j] = val;
    else        C_out[base + j - 16] = val;
  }
}

// ---------------- K2b: selective scan; 256 blocks x 512 thr; thread=(d,n) ----------------
__global__ __launch_bounds__(512) void k_scan(
    const float* __restrict__ u, const float* __restrict__ zs,
    const float* __restrict__ delta, const float* __restrict__ Bm,
    const float* __restrict__ Cm, const float* __restrict__ A_log,
    const float* __restrict__ Dp, float* __restrict__ ybar)
{
  __shared__ float dlT[32][68], uT[32][68], zT[32][68], BT[16][68], CT[16][68];
  int b = blockIdx.x >> 1, h = blockIdx.x & 1;
  int tid = threadIdx.x;
  int dl = tid >> 4, n = tid & 15;
  int d = (h << 5) + dl;
  float A = -__expf(A_log[(d << 4) + n]);
  float hst = 0.f, acc_n = 0.f, acc_u = 0.f;
  const float* ub = u     + ((size_t)b << 16);
  const float* zb = zs    + ((size_t)b << 16);
  const float* db = delta + ((size_t)b << 16);
  const float* Bb = Bm    + ((size_t)b << 14);
  const float* Cb = Cm    + ((size_t)b << 14);
  for (int c = 0; c < 16; c++) {
    __syncthreads();
    for (int i = tid; i < 2048; i += 512) {
      int t = i >> 5, dd = i & 31;
      int src = (c << 12) + (t << 6) + (h << 5) + dd;
      dlT[dd][t] = db[src];
      uT [dd][t] = ub[src];
      zT [dd][t] = zb[src];
    }
    for (int i = tid; i < 1024; i += 512) {
      int t = i >> 4, nn = i & 15;
      BT[nn][t] = Bb[(c << 10) + i];
      CT[nn][t] = Cb[(c << 10) + i];
    }
    __syncthreads();
    for (int tq = 0; tq < 64; tq += 4) {
      float4 dv = *reinterpret_cast<const float4*>(&dlT[dl][tq]);
      float4 uv = *reinterpret_cast<const float4*>(&uT[dl][tq]);
      float4 zv = *reinterpret_cast<const float4*>(&zT[dl][tq]);
      float4 Bv = *reinterpret_cast<const float4*>(&BT[n][tq]);
      float4 Cv = *reinterpret_cast<const float4*>(&CT[n][tq]);
      hst = fmaf(__expf(dv.x * A), hst, dv.x * uv.x * Bv.x);
      acc_n = fmaf(hst * Cv.x, zv.x, acc_n);  acc_u = fmaf(uv.x, zv.x, acc_u);
      hst = fmaf(__expf(dv.y * A), hst, dv.y * uv.y * Bv.y);
      acc_n = fmaf(hst * Cv.y, zv.y, acc_n);  acc_u = fmaf(uv.y, zv.y, acc_u);
      hst = fmaf(__expf(dv.z * A), hst, dv.z * uv.z * Bv.z);
      acc_n = fmaf(hst * Cv.z, zv.z, acc_n);  acc_u = fmaf(uv.z, zv.z, acc_u);
      hst = fmaf(__expf(dv.w * A), hst, dv.w * uv.w * Bv.w);
      acc_n = fmaf(hst * Cv.w, zv.w, acc_n);  acc_u = fmaf(uv.w, zv.w, acc_u);
    }
  }
  float y_n = acc_n;
  #pragma unroll
  for (int o = 8; o >= 1; o >>= 1) y_n += __shfl_xor(y_n, o, 16);
  if (n == 0) ybar[(b << 6) + d] = (y_n + Dp[d] * acc_u) * (1.f / 1024.f);
}

// ---------------- K3a: conv1 3x3 VALID (32->32) + BN1 + ReLU, MFMA, -> c1_bf -------------
// block = (b, 6-output-row strip); 4 waves; wave w: px-frags {w, w+4, w+8}, all 32 co
__global__ __launch_bounds__(256) void k_conv1m(
    const unsigned short* __restrict__ p_bf, const unsigned short* __restrict__ Wf1,
    const float* __restrict__ cbias,
    const float* __restrict__ g, const float* __restrict__ be,
    const float* __restrict__ mm, const float* __restrict__ vv,
    unsigned short* __restrict__ c1_bf)
{
  __shared__ __align__(16) unsigned short inS[8 * 32 * 40];  // [row][x][ci pad40]
  int b = blockIdx.x / 5, s = blockIdx.x % 5;
  int y0 = s * 6;
  int tid = threadIdx.x, lane = tid & 63, w = tid >> 6;
  int li = lane & 15, cig8 = (lane >> 4) << 3;
  for (int uu = tid; uu < 1024; uu += 256) {
    int r = uu >> 7, rem = uu & 127;
    uint4 v = *reinterpret_cast<const uint4*>(
        &p_bf[((((size_t)b << 10) + (y0 + r) * 32) << 5) + rem * 8]);
    int xx = rem >> 2, cg = rem & 3;
    *reinterpret_cast<uint4*>(&inS[(r * 32 + xx) * 40 + cg * 8]) = v;
  }
  bf16x8 aw[9][2];
  #pragma unroll
  for (int t = 0; t < 9; t++)
    #pragma unroll
    for (int m = 0; m < 2; m++)
      aw[t][m] = *reinterpret_cast<const bf16x8*>(&Wf1[(((t << 1) + m) * 64 + lane) * 8]);
  float scv[2][4], sbv[2][4];
  #pragma unroll
  for (int m = 0; m < 2; m++)
    #pragma unroll
    for (int j = 0; j < 4; j++) {
      int co = m * 16 + ((lane >> 4) << 2) + j;
      float sc = g[co] * rsqrtf(vv[co] + 1e-5f);
      scv[m][j] = sc;
      sbv[m][j] = fmaf(cbias[co] - mm[co], sc, be[co]);
    }
  __syncthreads();
  #pragma unroll
  for (int q = 0; q < 3; q++) {
    int pf = w + q * 4;
    int p = pf * 16 + li;
    int pv = (p < 180) ? p : 0;
    int ry = pv / 30, rx = pv % 30;
    f32x4 a0 = {0.f, 0.f, 0.f, 0.f}, a1 = {0.f, 0.f, 0.f, 0.f};
    #pragma unroll
    for (int t = 0; t < 9; t++) {
      int dy = t / 3, dx = t % 3;
      bf16x8 bfr = *reinterpret_cast<const bf16x8*>(
          &inS[((ry + dy) * 32 + rx + dx) * 40 + cig8]);
      a0 = MFMA16(aw[t][0], bfr, a0);
      a1 = MFMA16(aw[t][1], bfr, a1);
    }
    if (p < 180) {
      size_t obase = ((size_t)b * 900 + (size_t)(y0 + ry) * 30 + rx) << 5;
      #pragma unroll
      for (int m = 0; m < 2; m++) {
        f32x4 av = m ? a1 : a0;
        ushort4 pk;
        pk.x = f2bf(fmaxf(fmaf(av[0], scv[m][0], sbv[m][0]), 0.f));
        pk.y = f2bf(fmaxf(fmaf(av[1], scv[m][1], sbv[m][1]), 0.f));
        pk.z = f2bf(fmaxf(fmaf(av[2], scv[m][2], sbv[m][2]), 0.f));
        pk.w = f2bf(fmaxf(fmaf(av[3], scv[m][3], sbv[m][3]), 0.f));
        *reinterpret_cast<ushort4*>(&c1_bf[obase + m * 16 + ((lane >> 4) << 2)]) = pk;
      }
    }
  }
}

// ---------------- K3b: conv2 3x3 VALID (32->128) + BN2 + ReLU + spatial-sum, MFMA --------
// block = (b, 4-output-row strip); 4 waves; wave w: co 32w..32w+31, all 7 px-frags
__global__ __launch_bounds__(256) void k_conv2m(
    const unsigned short* __restrict__ c1_bf, const unsigned short* __restrict__ Wf2,
    const float* __restrict__ cb2,
    const float* __restrict__ g, const float* __restrict__ be,
    const float* __restrict__ mm, const float* __restrict__ vv,
    float* __restrict__ cnn_sum)
{
  __shared__ __align__(16) unsigned short inS[6 * 30 * 40];
  int b = blockIdx.x / 7, s = blockIdx.x % 7;
  int y0 = s * 4;
  int tid = threadIdx.x, lane = tid & 63, w = tid >> 6;
  int li = lane & 15, cig8 = (lane >> 4) << 3;
  for (int uu = tid; uu < 720; uu += 256) {
    int r = uu / 120, rem = uu % 120;
    uint4 v = *reinterpret_cast<const uint4*>(
        &c1_bf[(((size_t)b * 900 + (size_t)(y0 + r) * 30) << 5) + rem * 8]);
    int xx = rem >> 2, cg = rem & 3;
    *reinterpret_cast<uint4*>(&inS[(r * 30 + xx) * 40 + cg * 8]) = v;
  }
  bf16x8 aw[9][2];
  #pragma unroll
  for (int t = 0; t < 9; t++)
    #pragma unroll
    for (int m = 0; m < 2; m++)
      aw[t][m] = *reinterpret_cast<const bf16x8*>(&Wf2[(((t << 3) + (w << 1) + m) * 64 + lane) * 8]);
  float scv[2][4], sbv[2][4];
  float psum[2][4] = {{0.f,0.f,0.f,0.f},{0.f,0.f,0.f,0.f}};
  #pragma unroll
  for (int m = 0; m < 2; m++)
    #pragma unroll
    for (int j = 0; j < 4; j++) {
      int co = (w << 5) + m * 16 + ((lane >> 4) << 2) + j;
      float sc = g[co] * rsqrtf(vv[co] + 1e-5f);
      scv[m][j] = sc;
      sbv[m][j] = fmaf(cb2[co] - mm[co], sc, be[co]);
    }
  __syncthreads();
  #pragma unroll
  for (int pf = 0; pf < 7; pf++) {
    int p = pf * 16 + li;
    int ry = p / 28, rx = p % 28;
    f32x4 a0 = {0.f, 0.f, 0.f, 0.f}, a1 = {0.f, 0.f, 0.f, 0.f};
    #pragma unroll
    for (int t = 0; t < 9; t++) {
      int dy = t / 3, dx = t % 3;
      bf16x8 bfr = *reinterpret_cast<const bf16x8*>(
          &inS[((ry + dy) * 30 + rx + dx) * 40 + cig8]);
      a0 = MFMA16(aw[t][0], bfr, a0);
      a1 = MFMA16(aw[t][1], bfr, a1);
    }
    #pragma unroll
    for (int j = 0; j < 4; j++) {
      psum[0][j] += fmaxf(fmaf(a0[j], scv[0][j], sbv[0][j]), 0.f);
      psum[1][j] += fmaxf(fmaf(a1[j], scv[1][j], sbv[1][j]), 0.f);
    }
  }
  #pragma unroll
  for (int m = 0; m < 2; m++)
    #pragma unroll
    for (int j = 0; j < 4; j++) {
      float v = psum[m][j];
      v += __shfl_xor(v, 1); v += __shfl_xor(v, 2);
      v += __shfl_xor(v, 4); v += __shfl_xor(v, 8);
      if (li == 0) {
        int co = (w << 5) + m * 16 + ((lane >> 4) << 2) + j;
        atomicAdd(&cnn_sum[((size_t)b << 7) + co], v);
      }
    }
}

// ---------------- K4: out = ybar @ W2^T + fc_b + cnn_sum/784 ----------------
__global__ __launch_bounds__(256) void k_final(
    const float* __restrict__ ybar, const float* __restrict__ W2,
    const float* __restrict__ fc_b, const float* __restrict__ cnn_sum,
    float* __restrict__ out)
{
  int i = blockIdx.x * 256 + threadIdx.x;   // 16384
  int b = i >> 7, f = i & 127;
  float a = 0.f;
  #pragma unroll
  for (int d2 = 0; d2 < 64; d2++) a = fmaf(ybar[(b << 6) + d2], W2[(f << 6) + d2], a);
  out[i] = a + fc_b[f] + cnn_sum[i] * (1.f / 784.f);
}

extern "C" void kernel_launch(void* const* d_in, const int* in_sizes, int n_in,
                              void* d_out, int out_size, void* d_ws, size_t ws_size,
                              hipStream_t stream) {
  (void)in_sizes; (void)n_in; (void)out_size; (void)ws_size;
  const float* x         = (const float*)d_in[0];
  const float* proj_w    = (const float*)d_in[1];
  const float* proj_b    = (const float*)d_in[2];
  const float* bn0_g     = (const float*)d_in[3];
  const float* bn0_b     = (const float*)d_in[4];
  const float* bn0_m     = (const float*)d_in[5];
  const float* bn0_v     = (const float*)d_in[6];
  const float* in_proj_w = (const float*)d_in[7];
  const float* conv_w    = (const float*)d_in[8];
  const float* conv_b    = (const float*)d_in[9];
  const float* x_proj_w  = (const float*)d_in[10];
  const float* dt_w      = (const float*)d_in[11];
  const float* dt_b      = (const float*)d_in[12];
  const float* A_log     = (const float*)d_in[13];
  const float* Dp        = (const float*)d_in[14];
  const float* out_proj_w= (const float*)d_in[15];
  const float* fc_w      = (const float*)d_in[16];
  const float* fc_b      = (const float*)d_in[17];
  const float* c1_w      = (const float*)d_in[18];
  const float* c1_b      = (const float*)d_in[19];
  const float* bn1_g     = (const float*)d_in[20];
  const float* bn1_b     = (const float*)d_in[21];
  const float* bn1_m     = (const float*)d_in[22];
  const float* bn1_v     = (const float*)d_in[23];
  const float* c2_w      = (const float*)d_in[24];
  const float* c2_b      = (const float*)d_in[25];
  const float* bn2_g     = (const float*)d_in[26];
  const float* bn2_b     = (const float*)d_in[27];
  const float* bn2_m     = (const float*)d_in[28];
  const float* bn2_v     = (const float*)d_in[29];
  float* out = (float*)d_out;
  float* ws  = (float*)d_ws;
  // workspace layout (float slots); total ~37.55M floats = 150 MB
  float* p_tok   = ws;                          // 4194304
  float* u_b     = ws + 4194304;                // 8388608
  float* delta_b = ws + 12582912;               // 8388608
  float* zs_b    = ws + 20971520;               // 8388608
  float* Bm      = ws + 29360128;               // 2097152
  float* Cm      = ws + 31457280;               // 2097152
  float* ybar    = ws + 33554432;               // 8192
  float* cnn_sum = ws + 33562624;               // 16384
  float* W2      = ws + 33579008;               // 8192
  unsigned short* p_bf  = (unsigned short*)(ws + 33587200);  // 4194304 bf16
  unsigned short* c1_bf = (unsigned short*)(ws + 35684352);  // 3686400 bf16
  unsigned short* Wf1   = (unsigned short*)(ws + 37527552);  // 9216 bf16
  unsigned short* Wf2   = (unsigned short*)(ws + 37532160);  // 36864 bf16

  k_prep<<<dim3(276), dim3(256), 0, stream>>>(c1_w, c2_w, fc_w, out_proj_w, Wf1, Wf2, W2, cnn_sum);
  k_proj_bn<<<dim3(512), dim3(256), 0, stream>>>(x, proj_w, proj_b, bn0_g, bn0_b, bn0_m, bn0_v, p_tok, p_bf);
  k_mamba_pre<<<dim3(2048), dim3(256), 0, stream>>>(p_tok, in_proj_w, conv_w, conv_b, x_proj_w, dt_w, dt_b,
                                                    u_b, zs_b, delta_b, Bm, Cm);
  k_scan<<<dim3(256), dim3(512), 0, stream>>>(u_b, zs_b, delta_b, Bm, Cm, A_log, Dp, ybar);
  k_conv1m<<<dim3(640), dim3(256), 0, stream>>>(p_bf, Wf1, c1_b, bn1_g, bn1_b, bn1_m, bn1_v, c1_bf);
  k_conv2m<<<dim3(896), dim3(256), 0, stream>>>(c1_bf, Wf2, c2_b, bn2_g, bn2_b, bn2_m, bn2_v, cnn_sum);
  k_final<<<dim3(64), dim3(256), 0, stream>>>(ybar, W2, fc_b, cnn_sum, out);
}